// Round 1
// baseline (261.818 us; speedup 1.0000x reference)
//
#include <hip/hip_runtime.h>
#include <math.h>

// DigitCaps dynamic routing, MI355X (gfx950). Round 9: recompute-u pipeline.
// B=256, I=1152 (dim 8), O=10 (dim 16), 3 routing iters.
//
// Theory for this round: the fp16 u_hat tensor (94.4 MB written, 2x94.4 MB
// read) was 283 MB of the ~310 MB total HBM traffic, while recomputing
// u = W@x costs only ~755 MFLOP (~9 us of VALU in K1's proven structure,
// W served from L2/L3 per K1's FETCH=10.4MB counter). So: never materialize
// u_hat. Each routing iteration recomputes u in registers using the EXACT
// K1 register/LDS structure (80-float W fragment, 16x16 xs tile -- the only
// variant that doesn't spill) and does logits+softmax+sum(c*u) inline.
//
// b_ij identity: logits at iter k = u.(v0+..+v_{k-1}) = u.vsum, so each
// iteration only needs the running vsum [256][160] (L2-resident), computed
// by tiny reduce kernels between the heavy passes.
//
// Pipeline (single 11.8 MB partial buffer reused by all three passes):
//  K1 k_uhat_p0:  partial = sum_i u  (iter-0, uniform c)   [11.8 MB write]
//  K2 k_reduce<0>: v0 = squash(0.1*sum72 partial) -> vsumg (transposed)
//  K3 k_iter:      recompute u, c=softmax(u.v0),  partial = sum_i c*u
//  K4 k_reduce<1>: vsumg += squash(sum72 partial)          [vsum = v0+v1]
//  K5 k_iter:      recompute u, c=softmax(u.vsum), partial = sum_i c*u
//  K6 k_reduce<2>: out = squash(sum72 partial)
//
// All-fp32 path: absmax should drop well below the fp16-era 0.00195.

constexpr int Bc  = 256;
constexpr int Ic  = 1152;
constexpr int Oc  = 10;
constexpr int DOc = 16;
constexpr int ODc = 160;
constexpr int ITILES = 72;

// Sum over the aligned 16-lane group, result in all 16 lanes. Pure VALU (DPP).
__device__ __forceinline__ float dpp16_sum(float v) {
    int s;
    s = __builtin_amdgcn_update_dpp(0, __float_as_int(v), 0xB1, 0xF, 0xF, true);
    v += __int_as_float(s);
    s = __builtin_amdgcn_update_dpp(0, __float_as_int(v), 0x4E, 0xF, 0xF, true);
    v += __int_as_float(s);
    s = __builtin_amdgcn_update_dpp(0, __float_as_int(v), 0x124, 0xF, 0xF, true);
    v += __int_as_float(s);
    s = __builtin_amdgcn_update_dpp(0, __float_as_int(v), 0x128, 0xF, 0xF, true);
    v += __int_as_float(s);
    return v;
}

// ---------------------------------------------------------------- K1
// R4's proven k_uhat structure with the 94 MB fp16 uws store DELETED.
// grid 72 itiles x 16 btiles, 256 thr, LDS 48 KB -> 3 blocks/CU.
__global__ __launch_bounds__(256, 4) void k_uhat_p0(const float* __restrict__ x,
                                                    const float* __restrict__ W,
                                                    float* __restrict__ partial) {
    const int bx    = blockIdx.x;
    const int itile = bx % ITILES;
    const int btile = bx / ITILES;
    const int t     = threadIdx.x;
    const int d     = t & 15;
    const int il    = t >> 4;
    const int w     = t >> 6;
    const int i     = itile * 16 + il;
    const int b0    = btile * 16;

    __shared__ __align__(16) float xs[16 * 128];        //  8 KB [bb][il*8+k]
    __shared__ __align__(16) float pacc[4 * 16 * ODc];  // 40 KB [w][bb][od]

    // stage x[b0:b0+16][itile*16:+16][8]
#pragma unroll
    for (int j = 0; j < 2; ++j) {
        int e  = t + j * 256;
        int bb = e >> 5;
        int r  = e & 31;
        ((float4*)xs)[e] =
            ((const float4*)(x + (size_t)(b0 + bb) * (Ic * 8) + itile * 128))[r];
    }

    // W fragment for (i, d): 10 o x 8 k = 80 floats in registers
    float4 wr[20];
    {
        const float4* wp = (const float4*)(W + (((size_t)i * Oc) * DOc + d) * 8);
#pragma unroll
        for (int o = 0; o < Oc; ++o) {
            wr[2 * o]     = wp[o * 32];
            wr[2 * o + 1] = wp[o * 32 + 1];
        }
    }
    __syncthreads();

#pragma unroll 1
    for (int bb = 0; bb < 16; ++bb) {
        const float4 xa = *((const float4*)(xs + bb * 128 + il * 8));
        const float4 xb = *((const float4*)(xs + bb * 128 + il * 8 + 4));
        float u[Oc];
#pragma unroll
        for (int o = 0; o < Oc; ++o) {
            float4 w0 = wr[2 * o], w1 = wr[2 * o + 1];
            u[o] = w0.x * xa.x + w0.y * xa.y + w0.z * xa.z + w0.w * xa.w +
                   w1.x * xb.x + w1.y * xb.y + w1.z * xb.z + w1.w * xb.w;
        }
#pragma unroll
        for (int o = 0; o < Oc; ++o) {
            float a = u[o];
            a += __shfl_xor(a, 16);
            a += __shfl_xor(a, 32);
            if ((t & 63) < 16) pacc[(w * 16 + bb) * ODc + o * 16 + d] = a;
        }
    }
    __syncthreads();
#pragma unroll
    for (int j = 0; j < 10; ++j) {
        int e = t + j * 256;
        float s = pacc[e] + pacc[2560 + e] + pacc[5120 + e] + pacc[7680 + e];
        partial[(size_t)itile * (Bc * ODc) + b0 * ODc + e] = s;
    }
}

// ---------------------------------------------------------------- k_iter
// One routing iteration: recompute u (exact K1 structure), logits via DPP
// 16-lane reduce against vsum, softmax over o (replicated in d-lanes),
// accumulate sum_i c*u -> per-itile partials.
// LDS 48 KB caps occupancy at 3 blocks/CU = 3 waves/SIMD, so launch_bounds
// (256,3) gives the allocator 170 regs -> headroom for wr[20]+u+c+vr, no spill.
__global__ __launch_bounds__(256, 3) void k_iter(const float* __restrict__ x,
                                                 const float* __restrict__ W,
                                                 const float* __restrict__ vsum,
                                                 float* __restrict__ spart) {
    const int bx    = blockIdx.x;
    const int itile = bx % ITILES;
    const int btile = bx / ITILES;
    const int t     = threadIdx.x;
    const int d     = t & 15;
    const int il    = t >> 4;
    const int w     = t >> 6;
    const int i     = itile * 16 + il;
    const int b0    = btile * 16;

    __shared__ __align__(16) float xs[16 * 128];        //  8 KB
    __shared__ __align__(16) float pacc[4 * 16 * ODc];  // 40 KB

#pragma unroll
    for (int j = 0; j < 2; ++j) {
        int e  = t + j * 256;
        int bb = e >> 5;
        int r  = e & 31;
        ((float4*)xs)[e] =
            ((const float4*)(x + (size_t)(b0 + bb) * (Ic * 8) + itile * 128))[r];
    }

    float4 wr[20];
    {
        const float4* wp = (const float4*)(W + (((size_t)i * Oc) * DOc + d) * 8);
#pragma unroll
        for (int o = 0; o < Oc; ++o) {
            wr[2 * o]     = wp[o * 32];
            wr[2 * o + 1] = wp[o * 32 + 1];
        }
    }
    __syncthreads();

#pragma unroll 1
    for (int bb = 0; bb < 16; ++bb) {
        // vsum for this (b, d) -- transposed layout [b][d][16-slot], 16B aligned,
        // slots 0..9 hold o. 3 vector loads, L1/L2-cached (640 B per b).
        const float* vb = vsum + (size_t)(b0 + bb) * 256 + d * 16;
        const float4 va = *((const float4*)vb);
        const float4 vc = *((const float4*)(vb + 4));
        const float2 ve = *((const float2*)(vb + 8));
        float vr[Oc] = {va.x, va.y, va.z, va.w, vc.x, vc.y, vc.z, vc.w, ve.x, ve.y};

        const float4 xa = *((const float4*)(xs + bb * 128 + il * 8));
        const float4 xb = *((const float4*)(xs + bb * 128 + il * 8 + 4));
        float u[Oc];
#pragma unroll
        for (int o = 0; o < Oc; ++o) {
            float4 w0 = wr[2 * o], w1 = wr[2 * o + 1];
            u[o] = w0.x * xa.x + w0.y * xa.y + w0.z * xa.z + w0.w * xa.w +
                   w1.x * xb.x + w1.y * xb.y + w1.z * xb.z + w1.w * xb.w;
        }
        // logits l[o] = sum_d u*v  (16-lane DPP reduce, replicated in lanes)
        float c[Oc];
#pragma unroll
        for (int o = 0; o < Oc; ++o) c[o] = dpp16_sum(u[o] * vr[o]);
        float m = c[0];
#pragma unroll
        for (int o = 1; o < Oc; ++o) m = fmaxf(m, c[o]);
        float se = 0.f;
#pragma unroll
        for (int o = 0; o < Oc; ++o) {
            c[o] = __expf(c[o] - m);
            se += c[o];
        }
        const float inv = 1.f / se;
#pragma unroll
        for (int o = 0; o < Oc; ++o) {
            float a = (c[o] * inv) * u[o];
            a += __shfl_xor(a, 16);
            a += __shfl_xor(a, 32);
            if ((t & 63) < 16) pacc[(w * 16 + bb) * ODc + o * 16 + d] = a;
        }
    }
    __syncthreads();
#pragma unroll
    for (int j = 0; j < 10; ++j) {
        int e = t + j * 256;
        float s = pacc[e] + pacc[2560 + e] + pacc[5120 + e] + pacc[7680 + e];
        spart[(size_t)itile * (Bc * ODc) + b0 * ODc + e] = s;
    }
}

// ---------------------------------------------------------------- k_reduce
// Reduce 72 itile-partials -> s[b][160], squash, and either
//  P==0: vsumg (transposed [b][d][16]) = v            (s scaled by 0.1)
//  P==1: vsumg += v                                    (vsum = v0+v1)
//  P==2: out[b][o][d] = v                              (final output)
template <int P>
__global__ __launch_bounds__(192) void k_reduce(const float* __restrict__ part,
                                                float* __restrict__ vsumg,
                                                float* __restrict__ out) {
    const int b = blockIdx.x;
    const int t = threadIdx.x;
    if (t >= ODc) return;
    float s = 0.f;
    const float* pb = part + (size_t)b * ODc + t;
#pragma unroll
    for (int p = 0; p < ITILES; ++p) s += pb[(size_t)p * (Bc * ODc)];
    if (P == 0) s *= 0.1f;
    float sq = dpp16_sum(s * s);
    float v = s * (sq / ((1.f + sq) * sqrtf(sq)));
    if constexpr (P == 2) {
        out[(size_t)b * ODc + t] = v;
    } else {
        const int o = t >> 4, dd = t & 15;
        float* vp = vsumg + (size_t)b * 256 + dd * 16 + o;
        if constexpr (P == 0) *vp = v;
        else                  *vp += v;
    }
}

// ---------------------------------------------------------------- fallback
__global__ void __launch_bounds__(1024, 4)
digitcaps_fallback(const float* __restrict__ x, const float* __restrict__ W,
                   float* __restrict__ out) {
    const int b = blockIdx.x, t = threadIdx.x;
    const int lane = t & 63, wid = t >> 6, d = t & 15, iblk = t >> 4;
    __shared__ __align__(16) float xs[Ic * 8];
    __shared__ __align__(16) float red[16 * ODc];
    __shared__ __align__(16) float svec[ODc], vcur[ODc], vsum[ODc];
    {
        const float4* xg = (const float4*)(x + (size_t)b * (Ic * 8));
        float4* xl = (float4*)xs;
        for (int j = t; j < Ic * 2; j += 1024) xl[j] = xg[j];
    }
    if (t < ODc) vsum[t] = 0.f;
    __syncthreads();
    float acc[Oc], vsr[Oc];
    for (int it = 0; it < 3; ++it) {
#pragma unroll
        for (int o = 0; o < Oc; ++o) { acc[o] = 0.f; vsr[o] = vsum[o * 16 + d]; }
#pragma unroll 1
        for (int chk = 0; chk < 18; ++chk) {
            const int i = chk * 64 + iblk;
            const float4 xa = ((const float4*)(xs + i * 8))[0];
            const float4 xb = ((const float4*)(xs + i * 8))[1];
            const float* wb = W + (((size_t)i * Oc) * DOc + d) * 8;
            float uo[Oc];
#pragma unroll
            for (int o = 0; o < Oc; ++o) {
                const float4* wp = (const float4*)(wb + o * 128);
                float4 w0 = wp[0], w1 = wp[1];
                uo[o] = w0.x * xa.x + w0.y * xa.y + w0.z * xa.z + w0.w * xa.w +
                        w1.x * xb.x + w1.y * xb.y + w1.z * xb.z + w1.w * xb.w;
            }
            float cc[Oc];
            if (it > 0) {
#pragma unroll
                for (int o = 0; o < Oc; ++o) cc[o] = dpp16_sum(uo[o] * vsr[o]);
                float m = cc[0];
#pragma unroll
                for (int o = 1; o < Oc; ++o) m = fmaxf(m, cc[o]);
                float se = 0.f;
#pragma unroll
                for (int o = 0; o < Oc; ++o) { cc[o] = __expf(cc[o] - m); se += cc[o]; }
                float inv = 1.f / se;
#pragma unroll
                for (int o = 0; o < Oc; ++o) acc[o] += cc[o] * inv * uo[o];
            } else {
#pragma unroll
                for (int o = 0; o < Oc; ++o) acc[o] += 0.1f * uo[o];
            }
        }
#pragma unroll
        for (int o = 0; o < Oc; ++o) {
            float a = acc[o];
            a += __shfl_xor(a, 16);
            a += __shfl_xor(a, 32);
            if (lane < 16) red[wid * ODc + o * 16 + lane] = a;
        }
        __syncthreads();
        if (t < ODc) {
            float s = 0.f;
#pragma unroll
            for (int w = 0; w < 16; ++w) s += red[w * ODc + t];
            svec[t] = s;
        }
        __syncthreads();
        if (t < Oc) {
            float sq = 0.f;
#pragma unroll
            for (int dd = 0; dd < DOc; ++dd) sq += svec[t * 16 + dd] * svec[t * 16 + dd];
            float sc = sq / ((1.f + sq) * sqrtf(sq));
#pragma unroll
            for (int dd = 0; dd < DOc; ++dd) {
                float v = svec[t * 16 + dd] * sc;
                vcur[t * 16 + dd] = v;
                vsum[t * 16 + dd] += v;
            }
        }
        __syncthreads();
    }
    if (t < ODc) out[(size_t)b * ODc + t] = vcur[t];
}

// ---------------------------------------------------------------- launcher
extern "C" void kernel_launch(void* const* d_in, const int* in_sizes, int n_in,
                              void* d_out, int out_size, void* d_ws, size_t ws_size,
                              hipStream_t stream) {
    (void)in_sizes; (void)n_in; (void)out_size;
    const float* x = (const float*)d_in[0];   // [256,1152,8]
    const float* W = (const float*)d_in[1];   // [1152,10,16,8]
    float* out     = (float*)d_out;           // [256,10,16]

    const size_t PART_B = (size_t)ITILES * Bc * ODc * sizeof(float); // 11.80 MB
    const size_t VS_B   = (size_t)Bc * 256 * sizeof(float);          //  0.26 MB

    float* partial = (float*)d_ws;
    float* vsumg   = (float*)((char*)d_ws + PART_B);

    if (ws_size >= PART_B + VS_B) {
        hipLaunchKernelGGL(k_uhat_p0, dim3(ITILES * 16), dim3(256), 0, stream,
                           x, W, partial);
        hipLaunchKernelGGL((k_reduce<0>), dim3(Bc), dim3(192), 0, stream,
                           partial, vsumg, nullptr);
        hipLaunchKernelGGL(k_iter, dim3(ITILES * 16), dim3(256), 0, stream,
                           x, W, vsumg, partial);
        hipLaunchKernelGGL((k_reduce<1>), dim3(Bc), dim3(192), 0, stream,
                           partial, vsumg, nullptr);
        hipLaunchKernelGGL(k_iter, dim3(ITILES * 16), dim3(256), 0, stream,
                           x, W, vsumg, partial);
        hipLaunchKernelGGL((k_reduce<2>), dim3(Bc), dim3(192), 0, stream,
                           partial, nullptr, out);
    } else {
        hipLaunchKernelGGL(digitcaps_fallback, dim3(Bc), dim3(1024), 0, stream,
                           x, W, out);
    }
}